// Round 1
// baseline (28412.415 us; speedup 1.0000x reference)
//
#include <hip/hip_runtime.h>
#include <math.h>

#define N_NODES 100000
#define N_EDGES 1600000
#define NUM_GRAPHS 128
#define ATOM_IN 92
#define FEA 64
#define EDGE_DIM 41
#define ZDIM 169
#define N_CONV 5
#define HID 256
#define OUT_PER_G 384

#define HBYTES (N_NODES * FEA * 4)   // 25,600,000

__device__ __forceinline__ float sigmoidf_(float x) {
    return 1.0f / (1.0f + __expf(-x));
}
__device__ __forceinline__ float softplusf_(float x) {
    float a = fabsf(x);
    return fmaxf(x, 0.0f) + __logf(1.0f + __expf(-a));
}

// h = x @ embW + embB   [100000,92]@[92,64]
__global__ __launch_bounds__(256) void k_embed(const float* __restrict__ x,
                                               const float* __restrict__ W,
                                               const float* __restrict__ b,
                                               float* __restrict__ h) {
    int idx = blockIdx.x * 256 + threadIdx.x;
    int c = idx & 63;
    int n = __builtin_amdgcn_readfirstlane(idx >> 6);  // wave-uniform node id
    float acc = 0.0f;
#pragma unroll 4
    for (int k = 0; k < ATOM_IN; ++k)
        acc = fmaf(x[n * ATOM_IN + k], W[k * FEA + c], acc);
    h[idx] = acc + b[c];
}

// Edge message + atomic aggregate. 64 edges/block, 256 threads.
// z^T staged in LDS [169][65] (pad 65 -> conflict-free).
// wave 0,1: f = Wf cols [0..31],[32..63]; wave 2,3: s = Ws cols [0..31],[32..63].
__global__ __launch_bounds__(256) void k_edge(const float* __restrict__ h,
                                              const int* __restrict__ src,
                                              const int* __restrict__ dst,
                                              const float* __restrict__ ea,
                                              const float* __restrict__ Wf,
                                              const float* __restrict__ bf,
                                              const float* __restrict__ Ws,
                                              const float* __restrict__ bs,
                                              float* __restrict__ agg) {
    __shared__ float smem[ZDIM * 65];  // 43.9 KB; reused for s-activations
    __shared__ int edst[64], esrc[64];
    int t = threadIdx.x;
    int lane = t & 63;
    int w = t >> 6;
    int ebase = blockIdx.x * 64;
    if (t < 64) {
        edst[t] = dst[ebase + t];
        esrc[t] = src[ebase + t];
    }
    __syncthreads();
    // gather: lane = k index (coalesced row reads), e strided by wave
    for (int e = w; e < 64; e += 4) {
        int nd = edst[e], ns = esrc[e];
        smem[lane * 65 + e] = h[nd * FEA + lane];
        smem[(64 + lane) * 65 + e] = h[ns * FEA + lane];
        if (lane < EDGE_DIM)
            smem[(128 + lane) * 65 + e] = ea[(size_t)(ebase + e) * EDGE_DIM + lane];
    }
    __syncthreads();

    int wu = __builtin_amdgcn_readfirstlane(w);
    int cb = (wu & 1) * 32;
    const float* Wp = ((wu < 2) ? Wf : Ws) + cb;  // row stride FEA
    float acc[32];
#pragma unroll
    for (int j = 0; j < 32; ++j) acc[j] = 0.0f;

#pragma unroll 2
    for (int k = 0; k < ZDIM; ++k) {
        float zk = smem[k * 65 + lane];      // conflict-free (stride 1 across lanes)
        const float* wr = Wp + k * FEA;      // wave-uniform -> s_load broadcast
#pragma unroll
        for (int j = 0; j < 32; ++j) acc[j] = fmaf(zk, wr[j], acc[j]);
    }
    __syncthreads();  // everyone done reading z; smem reusable

    if (wu >= 2) {  // s half: softplus, publish via LDS
        const float* bsp = bs + cb;
#pragma unroll
        for (int j = 0; j < 32; ++j)
            smem[lane * 65 + cb + j] = softplusf_(acc[j] + bsp[j]);
    }
    __syncthreads();

    if (wu < 2) {  // f half: sigmoid, multiply, atomic aggregate at dst
        const float* bfp = bf + cb;
        int nd = edst[lane];
        float* aggp = agg + (size_t)nd * FEA + cb;
#pragma unroll
        for (int j = 0; j < 32; ++j) {
            float m = sigmoidf_(acc[j] + bfp[j]) * smem[lane * 65 + cb + j];
            atomicAdd(aggp + j, m);
        }
    }
}

// column sums / sumsq over agg [100000,64] -> stats[0..63]=sum, [64..127]=sumsq
__global__ __launch_bounds__(256) void k_bnstats(const float* __restrict__ agg,
                                                 float* __restrict__ stats) {
    int t = threadIdx.x, c = t & 63, w = t >> 6;
    float s = 0.0f, q = 0.0f;
    for (int r = blockIdx.x * 4 + w; r < N_NODES; r += gridDim.x * 4) {
        float v = agg[(size_t)r * FEA + c];
        s += v;
        q = fmaf(v, v, q);
    }
    __shared__ float red[2][256];
    red[0][t] = s;
    red[1][t] = q;
    __syncthreads();
    if (t < 64) {
        s = red[0][t] + red[0][t + 64] + red[0][t + 128] + red[0][t + 192];
        q = red[1][t] + red[1][t + 64] + red[1][t + 128] + red[1][t + 192];
        atomicAdd(&stats[t], s);
        atomicAdd(&stats[64 + t], q);
    }
}

// h += BN(agg) (training-stats batchnorm) ; elementwise
__global__ __launch_bounds__(256) void k_bnapply(const float* __restrict__ agg,
                                                 const float* __restrict__ stats,
                                                 const float* __restrict__ gamma,
                                                 const float* __restrict__ beta,
                                                 float* __restrict__ h) {
    int idx = blockIdx.x * 256 + threadIdx.x;
    int c = idx & 63;
    float mu = stats[c] * (1.0f / N_NODES);
    float var = stats[64 + c] * (1.0f / N_NODES) - mu * mu;
    float rs = rsqrtf(var + 1e-5f);
    float v = agg[idx];
    h[idx] += (v - mu) * rs * gamma[c] + beta[c];
}

// per-graph mean pool; batch is sorted -> binary search boundaries, no atomics
__global__ __launch_bounds__(256) void k_pool(const float* __restrict__ h,
                                              const int* __restrict__ batch,
                                              float* __restrict__ psum,
                                              float* __restrict__ pcnt) {
    int g = blockIdx.x;
    int lo, hi;
    {
        int a = 0, b = N_NODES;
        while (a < b) { int m = (a + b) >> 1; if (batch[m] < g) a = m + 1; else b = m; }
        lo = a;
    }
    {
        int a = lo, b = N_NODES;
        while (a < b) { int m = (a + b) >> 1; if (batch[m] < g + 1) a = m + 1; else b = m; }
        hi = a;
    }
    int t = threadIdx.x, c = t & 63, w = t >> 6;
    float s = 0.0f;
    for (int r = lo + w; r < hi; r += 4) s += h[(size_t)r * FEA + c];
    __shared__ float red[256];
    red[t] = s;
    __syncthreads();
    if (t < 64) {
        psum[g * FEA + t] = red[t] + red[t + 64] + red[t + 128] + red[t + 192];
        if (t == 0) pcnt[g] = (float)(hi - lo);
    }
}

// head MLP: one block per graph
__global__ __launch_bounds__(256) void k_head(const float* __restrict__ psum,
                                              const float* __restrict__ pcnt,
                                              const float* __restrict__ W1, const float* __restrict__ b1,
                                              const float* __restrict__ W2, const float* __restrict__ b2,
                                              const float* __restrict__ W3, const float* __restrict__ b3,
                                              float* __restrict__ out) {
    int g = blockIdx.x, t = threadIdx.x;
    __shared__ float p[64], g1[256], g2[256];
    if (t < 64) p[t] = psum[g * FEA + t] / fmaxf(pcnt[g], 1.0f);
    __syncthreads();
    {
        float acc = b1[t];
#pragma unroll 8
        for (int k = 0; k < FEA; ++k) acc = fmaf(p[k], W1[k * HID + t], acc);
        g1[t] = softplusf_(acc);
    }
    __syncthreads();
    {
        float acc = b2[t];
#pragma unroll 8
        for (int k = 0; k < HID; ++k) acc = fmaf(g1[k], W2[k * HID + t], acc);
        g2[t] = softplusf_(acc);
    }
    __syncthreads();
    for (int c = t; c < OUT_PER_G; c += 256) {
        float acc = b3[c];
#pragma unroll 8
        for (int k = 0; k < HID; ++k) acc = fmaf(g2[k], W3[k * OUT_PER_G + c], acc);
        out[g * OUT_PER_G + c] = acc;
    }
}

extern "C" void kernel_launch(void* const* d_in, const int* in_sizes, int n_in,
                              void* d_out, int out_size, void* d_ws, size_t ws_size,
                              hipStream_t stream) {
    (void)in_sizes; (void)n_in; (void)out_size; (void)ws_size;
    const float* x    = (const float*)d_in[0];
    const int*   ei   = (const int*)d_in[1];
    const float* ea   = (const float*)d_in[2];
    const int*   batch= (const int*)d_in[3];
    const float* embW = (const float*)d_in[4];
    const float* embB = (const float*)d_in[5];
    const float* lfW  = (const float*)d_in[6];
    const float* lfB  = (const float*)d_in[7];
    const float* lsW  = (const float*)d_in[8];
    const float* lsB  = (const float*)d_in[9];
    const float* gam  = (const float*)d_in[10];
    const float* bet  = (const float*)d_in[11];
    const float* W1 = (const float*)d_in[12];
    const float* b1 = (const float*)d_in[13];
    const float* W2 = (const float*)d_in[14];
    const float* b2 = (const float*)d_in[15];
    const float* W3 = (const float*)d_in[16];
    const float* b3 = (const float*)d_in[17];

    const int* srcI = ei;             // edge_index[0] = source (x_j)
    const int* dstI = ei + N_EDGES;   // edge_index[1] = target (x_i, aggregate here)

    char* ws = (char*)d_ws;
    float* h     = (float*)(ws);                       // 25,600,000 B
    float* agg   = (float*)(ws + HBYTES);              // 25,600,000 B
    float* stats = (float*)(ws + 2 * (size_t)HBYTES);  // 512 B (contiguous after agg)
    float* psum  = (float*)(ws + 2 * (size_t)HBYTES + 512);        // 32768 B
    float* pcnt  = (float*)(ws + 2 * (size_t)HBYTES + 512 + 32768);// 512 B

    k_embed<<<N_NODES * FEA / 256, 256, 0, stream>>>(x, embW, embB, h);

    for (int L = 0; L < N_CONV; ++L) {
        hipMemsetAsync(agg, 0, (size_t)HBYTES + 512, stream);  // agg + stats
        k_edge<<<N_EDGES / 64, 256, 0, stream>>>(h, srcI, dstI, ea,
                                                 lfW + (size_t)L * ZDIM * FEA, lfB + L * FEA,
                                                 lsW + (size_t)L * ZDIM * FEA, lsB + L * FEA,
                                                 agg);
        k_bnstats<<<256, 256, 0, stream>>>(agg, stats);
        k_bnapply<<<N_NODES * FEA / 256, 256, 0, stream>>>(agg, stats,
                                                           gam + L * FEA, bet + L * FEA, h);
    }

    k_pool<<<NUM_GRAPHS, 256, 0, stream>>>(h, batch, psum, pcnt);
    k_head<<<NUM_GRAPHS, 256, 0, stream>>>(psum, pcnt, W1, b1, W2, b2, W3, b3,
                                           (float*)d_out);
}

// Round 2
// 3828.386 us; speedup vs baseline: 7.4215x; 7.4215x over previous
//
#include <hip/hip_runtime.h>
#include <math.h>

#define N_NODES 100000
#define N_EDGES 1600000
#define NUM_GRAPHS 128
#define ATOM_IN 92
#define FEA 64
#define EDGE_DIM 41
#define ZDIM 169
#define N_CONV 5
#define HID 256
#define OUT_PER_G 384
#define NPAD 100096      // 391 * 256
#define NBLK 391

#define HBYTES ((size_t)N_NODES * FEA * 4)   // 25,600,000

__device__ __forceinline__ float sigmoidf_(float x) {
    return 1.0f / (1.0f + __expf(-x));
}
__device__ __forceinline__ float softplusf_(float x) {
    float a = fabsf(x);
    return fmaxf(x, 0.0f) + __logf(1.0f + __expf(-a));
}

// ---------------- embed: h = x @ embW + embB ----------------
__global__ __launch_bounds__(256) void k_embed(const float* __restrict__ x,
                                               const float* __restrict__ W,
                                               const float* __restrict__ b,
                                               float* __restrict__ h) {
    int idx = blockIdx.x * 256 + threadIdx.x;
    int c = idx & 63;
    int n = __builtin_amdgcn_readfirstlane(idx >> 6);
    float acc = 0.0f;
#pragma unroll 4
    for (int k = 0; k < ATOM_IN; ++k)
        acc = fmaf(x[n * ATOM_IN + k], W[k * FEA + c], acc);
    h[idx] = acc + b[c];
}

// ---------------- counting sort of edges by dst ----------------
__global__ __launch_bounds__(256) void k_hist(const int* __restrict__ dst,
                                              int* __restrict__ cnt) {
    int e = blockIdx.x * 256 + threadIdx.x;
    if (e < N_EDGES) atomicAdd(&cnt[dst[e]], 1);
}

__global__ __launch_bounds__(256) void k_blocksum(const int* __restrict__ cnt,
                                                  int* __restrict__ bsum) {
    __shared__ int s[256];
    int t = threadIdx.x;
    s[t] = cnt[blockIdx.x * 256 + t];
    __syncthreads();
    for (int o = 128; o > 0; o >>= 1) {
        if (t < o) s[t] += s[t + o];
        __syncthreads();
    }
    if (t == 0) bsum[blockIdx.x] = s[0];
}

__global__ __launch_bounds__(512) void k_topscan(int* __restrict__ bsum) {
    __shared__ int s[512];
    int t = threadIdx.x;
    int v = (t < NBLK) ? bsum[t] : 0;
    s[t] = v;
    __syncthreads();
    for (int o = 1; o < 512; o <<= 1) {
        int x = (t >= o) ? s[t - o] : 0;
        __syncthreads();
        s[t] += x;
        __syncthreads();
    }
    if (t < NBLK) bsum[t] = s[t] - v;  // exclusive
}

__global__ __launch_bounds__(256) void k_localscan(const int* __restrict__ cnt,
                                                   const int* __restrict__ bsum,
                                                   int* __restrict__ offs) {
    __shared__ int s[256];
    int t = threadIdx.x;
    int i = blockIdx.x * 256 + t;
    int v = cnt[i];
    s[t] = v;
    __syncthreads();
    for (int o = 1; o < 256; o <<= 1) {
        int x = (t >= o) ? s[t - o] : 0;
        __syncthreads();
        s[t] += x;
        __syncthreads();
    }
    offs[i] = bsum[blockIdx.x] + s[t] - v;  // exclusive prefix
}

__global__ __launch_bounds__(256) void k_scatter(const int* __restrict__ dst,
                                                 const int* __restrict__ src,
                                                 const int* __restrict__ offs,
                                                 int* __restrict__ cursor,
                                                 int* __restrict__ dstS,
                                                 int* __restrict__ srcS,
                                                 int* __restrict__ eidS) {
    int e = blockIdx.x * 256 + threadIdx.x;
    if (e >= N_EDGES) return;
    int d = dst[e];
    int p = offs[d] + atomicAdd(&cursor[d], 1);
    dstS[p] = d;
    srcS[p] = src[e];
    eidS[p] = e;
}

// ---------------- per-layer node projection ----------------
// P[n, 0:64]   = h[n] @ Wf[0:64]    (f, dst part)
// P[n, 64:128] = h[n] @ Ws[0:64]    (s, dst part)
// P[n,128:192] = h[n] @ Wf[64:128]  (f, src part)
// P[n,192:256] = h[n] @ Ws[64:128]  (s, src part)
__global__ __launch_bounds__(256) void k_nodegemm(const float* __restrict__ h,
                                                  const float* __restrict__ Wf,
                                                  const float* __restrict__ Ws,
                                                  float* __restrict__ P) {
    int t = threadIdx.x;
    int n = blockIdx.x;
    int sec = t >> 6, j = t & 63;
    const float* W = (sec == 0) ? Wf
                   : (sec == 1) ? Ws
                   : (sec == 2) ? (Wf + 64 * FEA)
                                : (Ws + 64 * FEA);
    __shared__ float hr[FEA];
    if (t < FEA) hr[t] = h[(size_t)n * FEA + t];
    __syncthreads();
    float acc = 0.0f;
#pragma unroll
    for (int k = 0; k < FEA; ++k) acc = fmaf(hr[k], W[k * FEA + j], acc);
    P[(size_t)n * 256 + t] = acc;
}

// ---------------- edge kernel (sorted by dst) ----------------
// block = 64 sorted edges, 4 waves.
// waves 0,1: f cols [0:32),[32:64); waves 2,3: s cols [0:32),[32:64).
__global__ __launch_bounds__(256) void k_edge(const float* __restrict__ P,
                                              const int* __restrict__ dstS,
                                              const int* __restrict__ srcS,
                                              const int* __restrict__ eidS,
                                              const float* __restrict__ ea,
                                              const float* __restrict__ Wf,
                                              const float* __restrict__ bf,
                                              const float* __restrict__ Ws,
                                              const float* __restrict__ bs,
                                              float* __restrict__ agg) {
    __shared__ float smem[64 * 65];  // eaT [41][65] during GEMM, then msg [64][65]
    __shared__ int ds_sh[64], ss_sh[64], eid_sh[64];
    int t = threadIdx.x;
    int lane = t & 63;
    int w = t >> 6;
    int wu = __builtin_amdgcn_readfirstlane(w);
    int ebase = blockIdx.x * 64;

    if (t < 64) {
        ds_sh[t] = dstS[ebase + t];
        ss_sh[t] = srcS[ebase + t];
        eid_sh[t] = eidS[ebase + t];
    }
    __syncthreads();

    // gather ea^T (rows via original edge id)
    for (int e = w; e < 64; e += 4) {
        if (lane < EDGE_DIM)
            smem[lane * 65 + e] = ea[(size_t)eid_sh[e] * EDGE_DIM + lane];
    }
    __syncthreads();

    bool isf = (wu < 2);
    int cb = (wu & 1) * 32;
    const float* We = (isf ? Wf : Ws) + 128 * FEA + cb;  // edge-part rows

    float acc[32];
#pragma unroll
    for (int j = 0; j < 32; ++j) acc[j] = 0.0f;
#pragma unroll 1
    for (int k = 0; k < EDGE_DIM; ++k) {
        float zk = smem[k * 65 + lane];
        const float* wr = We + k * FEA;
#pragma unroll
        for (int j = 0; j < 32; ++j) acc[j] = fmaf(zk, wr[j], acc[j]);
    }

    // add node parts + bias
    {
        int d = ds_sh[lane], s = ss_sh[lane];
        const float4* pd = (const float4*)(P + (size_t)d * 256 + (isf ? 0 : 64) + cb);
        const float4* ps = (const float4*)(P + (size_t)s * 256 + (isf ? 128 : 192) + cb);
        const float* bias = (isf ? bf : bs) + cb;
#pragma unroll
        for (int i = 0; i < 8; ++i) {
            float4 a = pd[i];
            float4 b2 = ps[i];
            acc[4 * i + 0] += a.x + b2.x + bias[4 * i + 0];
            acc[4 * i + 1] += a.y + b2.y + bias[4 * i + 1];
            acc[4 * i + 2] += a.z + b2.z + bias[4 * i + 2];
            acc[4 * i + 3] += a.w + b2.w + bias[4 * i + 3];
        }
    }

    __syncthreads();  // all eaT reads done; smem reusable as msg

    if (!isf) {  // s half: publish softplus
#pragma unroll
        for (int j = 0; j < 32; ++j)
            smem[lane * 65 + cb + j] = softplusf_(acc[j]);
    }
    __syncthreads();

    if (isf) {  // f half: msg = sigmoid(f) * softplus(s), overwrite in place
#pragma unroll
        for (int j = 0; j < 32; ++j) {
            float m = sigmoidf_(acc[j]) * smem[lane * 65 + cb + j];
            smem[lane * 65 + cb + j] = m;
        }
    }
    __syncthreads();

    // aggregation: wave w handles edges [w*16, w*16+16), lane = column.
    // dst-sorted -> run-accumulate in a register, one 64-lane contiguous
    // atomic burst per distinct dst.
    {
        int e0 = w * 16;
        int cur = __builtin_amdgcn_readfirstlane(ds_sh[e0]);
        float a = 0.0f;
        for (int e = e0; e < e0 + 16; ++e) {
            a += smem[e * 65 + lane];
            int nxt = (e + 1 < e0 + 16) ? __builtin_amdgcn_readfirstlane(ds_sh[e + 1]) : -1;
            if (nxt != cur) {
                atomicAdd(&agg[(size_t)cur * FEA + lane], a);
                a = 0.0f;
                cur = nxt;
            }
        }
    }
}

// ---------------- BN stats / apply ----------------
__global__ __launch_bounds__(256) void k_bnstats(const float* __restrict__ agg,
                                                 float* __restrict__ stats) {
    int t = threadIdx.x, c = t & 63, w = t >> 6;
    float s = 0.0f, q = 0.0f;
    for (int r = blockIdx.x * 4 + w; r < N_NODES; r += gridDim.x * 4) {
        float v = agg[(size_t)r * FEA + c];
        s += v;
        q = fmaf(v, v, q);
    }
    __shared__ float red[2][256];
    red[0][t] = s;
    red[1][t] = q;
    __syncthreads();
    if (t < 64) {
        s = red[0][t] + red[0][t + 64] + red[0][t + 128] + red[0][t + 192];
        q = red[1][t] + red[1][t + 64] + red[1][t + 128] + red[1][t + 192];
        atomicAdd(&stats[t], s);
        atomicAdd(&stats[64 + t], q);
    }
}

__global__ __launch_bounds__(256) void k_bnapply(const float* __restrict__ agg,
                                                 const float* __restrict__ stats,
                                                 const float* __restrict__ gamma,
                                                 const float* __restrict__ beta,
                                                 float* __restrict__ h) {
    int idx = blockIdx.x * 256 + threadIdx.x;
    int c = idx & 63;
    float mu = stats[c] * (1.0f / N_NODES);
    float var = stats[64 + c] * (1.0f / N_NODES) - mu * mu;
    float rs = rsqrtf(var + 1e-5f);
    float v = agg[idx];
    h[idx] += (v - mu) * rs * gamma[c] + beta[c];
}

// ---------------- pool + head ----------------
__global__ __launch_bounds__(256) void k_pool(const float* __restrict__ h,
                                              const int* __restrict__ batch,
                                              float* __restrict__ psum,
                                              float* __restrict__ pcnt) {
    int g = blockIdx.x;
    int lo, hi;
    {
        int a = 0, b = N_NODES;
        while (a < b) { int m = (a + b) >> 1; if (batch[m] < g) a = m + 1; else b = m; }
        lo = a;
    }
    {
        int a = lo, b = N_NODES;
        while (a < b) { int m = (a + b) >> 1; if (batch[m] < g + 1) a = m + 1; else b = m; }
        hi = a;
    }
    int t = threadIdx.x, c = t & 63, w = t >> 6;
    float s = 0.0f;
    for (int r = lo + w; r < hi; r += 4) s += h[(size_t)r * FEA + c];
    __shared__ float red[256];
    red[t] = s;
    __syncthreads();
    if (t < 64) {
        psum[g * FEA + t] = red[t] + red[t + 64] + red[t + 128] + red[t + 192];
        if (t == 0) pcnt[g] = (float)(hi - lo);
    }
}

__global__ __launch_bounds__(256) void k_head(const float* __restrict__ psum,
                                              const float* __restrict__ pcnt,
                                              const float* __restrict__ W1, const float* __restrict__ b1,
                                              const float* __restrict__ W2, const float* __restrict__ b2,
                                              const float* __restrict__ W3, const float* __restrict__ b3,
                                              float* __restrict__ out) {
    int g = blockIdx.x, t = threadIdx.x;
    __shared__ float p[64], g1[256], g2[256];
    if (t < 64) p[t] = psum[g * FEA + t] / fmaxf(pcnt[g], 1.0f);
    __syncthreads();
    {
        float acc = b1[t];
#pragma unroll 8
        for (int k = 0; k < FEA; ++k) acc = fmaf(p[k], W1[k * HID + t], acc);
        g1[t] = softplusf_(acc);
    }
    __syncthreads();
    {
        float acc = b2[t];
#pragma unroll 8
        for (int k = 0; k < HID; ++k) acc = fmaf(g1[k], W2[k * HID + t], acc);
        g2[t] = softplusf_(acc);
    }
    __syncthreads();
    for (int c = t; c < OUT_PER_G; c += 256) {
        float acc = b3[c];
#pragma unroll 8
        for (int k = 0; k < HID; ++k) acc = fmaf(g2[k], W3[k * OUT_PER_G + c], acc);
        out[g * OUT_PER_G + c] = acc;
    }
}

extern "C" void kernel_launch(void* const* d_in, const int* in_sizes, int n_in,
                              void* d_out, int out_size, void* d_ws, size_t ws_size,
                              hipStream_t stream) {
    (void)in_sizes; (void)n_in; (void)out_size; (void)ws_size;
    const float* x    = (const float*)d_in[0];
    const int*   ei   = (const int*)d_in[1];
    const float* ea   = (const float*)d_in[2];
    const int*   batch= (const int*)d_in[3];
    const float* embW = (const float*)d_in[4];
    const float* embB = (const float*)d_in[5];
    const float* lfW  = (const float*)d_in[6];
    const float* lfB  = (const float*)d_in[7];
    const float* lsW  = (const float*)d_in[8];
    const float* lsB  = (const float*)d_in[9];
    const float* gam  = (const float*)d_in[10];
    const float* bet  = (const float*)d_in[11];
    const float* W1 = (const float*)d_in[12];
    const float* b1 = (const float*)d_in[13];
    const float* W2 = (const float*)d_in[14];
    const float* b2 = (const float*)d_in[15];
    const float* W3 = (const float*)d_in[16];
    const float* b3 = (const float*)d_in[17];

    const int* srcI = ei;             // edge_index[0] = source (x_j)
    const int* dstI = ei + N_EDGES;   // edge_index[1] = target (x_i)

    char* ws = (char*)d_ws;
    size_t off = 0;
    float* h      = (float*)(ws + off); off += HBYTES;                  // 25.6 MB
    float* agg    = (float*)(ws + off); off += HBYTES;                  // 25.6 MB
    float* stats  = (float*)(ws + off); off += 512;                     // after agg (joint memset)
    float* psum   = (float*)(ws + off); off += 32768;
    float* pcnt   = (float*)(ws + off); off += 512;
    float* P      = (float*)(ws + off); off += (size_t)N_NODES * 256 * 4;  // 102.4 MB
    int*   cnt    = (int*)(ws + off);   off += (size_t)NPAD * 4;
    int*   bsum   = (int*)(ws + off);   off += 2048;
    int*   offs   = (int*)(ws + off);   off += (size_t)NPAD * 4;
    int*   cursor = (int*)(ws + off);   off += (size_t)NPAD * 4;
    int*   dstS   = (int*)(ws + off);   off += (size_t)N_EDGES * 4;
    int*   srcS   = (int*)(ws + off);   off += (size_t)N_EDGES * 4;
    int*   eidS   = (int*)(ws + off);   off += (size_t)N_EDGES * 4;

    // ---- sort edges by dst (once; reused across layers) ----
    hipMemsetAsync(cnt, 0, (size_t)NPAD * 4, stream);
    hipMemsetAsync(cursor, 0, (size_t)NPAD * 4, stream);
    k_hist<<<(N_EDGES + 255) / 256, 256, 0, stream>>>(dstI, cnt);
    k_blocksum<<<NBLK, 256, 0, stream>>>(cnt, bsum);
    k_topscan<<<1, 512, 0, stream>>>(bsum);
    k_localscan<<<NBLK, 256, 0, stream>>>(cnt, bsum, offs);
    k_scatter<<<(N_EDGES + 255) / 256, 256, 0, stream>>>(dstI, srcI, offs, cursor,
                                                         dstS, srcS, eidS);

    k_embed<<<N_NODES * FEA / 256, 256, 0, stream>>>(x, embW, embB, h);

    for (int L = 0; L < N_CONV; ++L) {
        const float* Wf = lfW + (size_t)L * ZDIM * FEA;
        const float* Ws = lsW + (size_t)L * ZDIM * FEA;
        k_nodegemm<<<N_NODES, 256, 0, stream>>>(h, Wf, Ws, P);
        hipMemsetAsync(agg, 0, HBYTES + 512, stream);  // agg + stats
        k_edge<<<N_EDGES / 64, 256, 0, stream>>>(P, dstS, srcS, eidS, ea,
                                                 Wf, lfB + L * FEA,
                                                 Ws, lsB + L * FEA,
                                                 agg);
        k_bnstats<<<256, 256, 0, stream>>>(agg, stats);
        k_bnapply<<<N_NODES * FEA / 256, 256, 0, stream>>>(agg, stats,
                                                           gam + L * FEA, bet + L * FEA, h);
    }

    k_pool<<<NUM_GRAPHS, 256, 0, stream>>>(h, batch, psum, pcnt);
    k_head<<<NUM_GRAPHS, 256, 0, stream>>>(psum, pcnt, W1, b1, W2, b2, W3, b3,
                                           (float*)d_out);
}

// Round 3
// 2145.431 us; speedup vs baseline: 13.2432x; 1.7844x over previous
//
#include <hip/hip_runtime.h>
#include <math.h>

#define N_NODES 100000
#define N_EDGES 1600000
#define NUM_GRAPHS 128
#define ATOM_IN 92
#define FEA 64
#define EDGE_DIM 41
#define ZDIM 169
#define KPAD 192        // 64 h_dst + 64 h_src + 64 ea(padded)
#define N_CONV 5
#define HID 256
#define OUT_PER_G 384
#define NPAD 100096      // 391 * 256
#define NBLK 391
#define ESTRIDE 200      // bf16 elems per z row in LDS (192 + 8 pad: conflict-free)

#define HBYTES ((size_t)N_NODES * FEA * 4)   // 25,600,000

typedef __attribute__((ext_vector_type(8))) short bf16x8;
typedef __attribute__((ext_vector_type(4))) float f32x4;

__device__ __forceinline__ float sigmoidf_(float x) {
    return 1.0f / (1.0f + __expf(-x));
}
__device__ __forceinline__ float softplusf_(float x) {
    float a = fabsf(x);
    return fmaxf(x, 0.0f) + __logf(1.0f + __expf(-a));
}
__device__ __forceinline__ unsigned short f2bf(float f) {
    unsigned int u = __float_as_uint(f);
    u = (u + 0x7FFFu + ((u >> 16) & 1u)) >> 16;   // round-nearest-even
    return (unsigned short)u;
}

// ---------------- embed: h = x @ embW + embB (writes fp32 + bf16 copy) ------
__global__ __launch_bounds__(256) void k_embed(const float* __restrict__ x,
                                               const float* __restrict__ W,
                                               const float* __restrict__ b,
                                               float* __restrict__ h,
                                               unsigned short* __restrict__ hb) {
    int idx = blockIdx.x * 256 + threadIdx.x;
    int c = idx & 63;
    int n = __builtin_amdgcn_readfirstlane(idx >> 6);
    float acc = 0.0f;
#pragma unroll 4
    for (int k = 0; k < ATOM_IN; ++k)
        acc = fmaf(x[n * ATOM_IN + k], W[k * FEA + c], acc);
    acc += b[c];
    h[idx] = acc;
    hb[idx] = f2bf(acc);
}

// ---------------- counting sort of edges by dst ----------------
__global__ __launch_bounds__(256) void k_hist(const int* __restrict__ dst,
                                              int* __restrict__ cnt) {
    int e = blockIdx.x * 256 + threadIdx.x;
    if (e < N_EDGES) atomicAdd(&cnt[dst[e]], 1);
}

__global__ __launch_bounds__(256) void k_blocksum(const int* __restrict__ cnt,
                                                  int* __restrict__ bsum) {
    __shared__ int s[256];
    int t = threadIdx.x;
    s[t] = cnt[blockIdx.x * 256 + t];
    __syncthreads();
    for (int o = 128; o > 0; o >>= 1) {
        if (t < o) s[t] += s[t + o];
        __syncthreads();
    }
    if (t == 0) bsum[blockIdx.x] = s[0];
}

__global__ __launch_bounds__(512) void k_topscan(int* __restrict__ bsum) {
    __shared__ int s[512];
    int t = threadIdx.x;
    int v = (t < NBLK) ? bsum[t] : 0;
    s[t] = v;
    __syncthreads();
    for (int o = 1; o < 512; o <<= 1) {
        int x = (t >= o) ? s[t - o] : 0;
        __syncthreads();
        s[t] += x;
        __syncthreads();
    }
    if (t < NBLK) bsum[t] = s[t] - v;  // exclusive
}

__global__ __launch_bounds__(256) void k_localscan(const int* __restrict__ cnt,
                                                   const int* __restrict__ bsum,
                                                   int* __restrict__ offs) {
    __shared__ int s[256];
    int t = threadIdx.x;
    int i = blockIdx.x * 256 + t;
    int v = cnt[i];
    s[t] = v;
    __syncthreads();
    for (int o = 1; o < 256; o <<= 1) {
        int x = (t >= o) ? s[t - o] : 0;
        __syncthreads();
        s[t] += x;
        __syncthreads();
    }
    offs[i] = bsum[blockIdx.x] + s[t] - v;  // exclusive prefix
}

__global__ __launch_bounds__(256) void k_scatter(const int* __restrict__ dst,
                                                 const int* __restrict__ src,
                                                 const int* __restrict__ offs,
                                                 int* __restrict__ cursor,
                                                 int* __restrict__ dstS,
                                                 int* __restrict__ srcS,
                                                 int* __restrict__ eidS) {
    int e = blockIdx.x * 256 + threadIdx.x;
    if (e >= N_EDGES) return;
    int d = dst[e];
    int p = offs[d] + atomicAdd(&cursor[d], 1);
    dstS[p] = d;
    srcS[p] = src[e];
    eidS[p] = e;
}

// ---------------- pre-sorted, zero-padded bf16 edge attrs -------------------
// eaSb[p][0:41] = bf16(ea[eidS[p]]); [41:64) = 0.  One wave per edge.
__global__ __launch_bounds__(256) void k_eaprep(const float* __restrict__ ea,
                                                const int* __restrict__ eidS,
                                                unsigned short* __restrict__ out) {
    int p = blockIdx.x * 4 + (threadIdx.x >> 6);
    int l = threadIdx.x & 63;
    int eid = eidS[p];
    float v = (l < EDGE_DIM) ? ea[(size_t)eid * EDGE_DIM + l] : 0.0f;
    out[(size_t)p * 64 + l] = f2bf(v);
}

// ---------------- weight pack: WbT[L][c][k] = bf16(W[k][c]), k>=169 -> 0 ----
// c in [0,64) -> Wf col c ; c in [64,128) -> Ws col c-64.
__global__ __launch_bounds__(256) void k_wprep(const float* __restrict__ lfW,
                                               const float* __restrict__ lsW,
                                               unsigned short* __restrict__ WbT) {
    int idx = blockIdx.x * 256 + threadIdx.x;
    if (idx >= N_CONV * 128 * KPAD) return;
    int k = idx % KPAD;
    int c = (idx / KPAD) % 128;
    int L = idx / (KPAD * 128);
    float v = 0.0f;
    if (k < ZDIM) {
        const float* W = ((c < 64) ? lfW : lsW) + (size_t)L * ZDIM * FEA;
        v = W[k * FEA + (c & 63)];
    }
    WbT[idx] = f2bf(v);
}

// ---------------- edge kernel: MFMA over z=[h_d|h_s|ea] (bf16) --------------
// block = 64 dst-sorted edges, 4 waves. Wave w owns output cols [32w,32w+32):
// w 0,1 -> f (cols 0..63), w 2,3 -> s (cols 0..63 of Ws).
__global__ __launch_bounds__(256) void k_edge(const unsigned short* __restrict__ hb,
                                              const int* __restrict__ dstS,
                                              const int* __restrict__ srcS,
                                              const unsigned short* __restrict__ eaSb,
                                              const unsigned short* __restrict__ WbT,
                                              const float* __restrict__ bfv,
                                              const float* __restrict__ bsv,
                                              float* __restrict__ agg) {
    __shared__ unsigned short z[64 * ESTRIDE];   // 25.6 KB; reused as msg after MFMA
    __shared__ int dsh[64], ssh[64];
    __shared__ float biasf[64], biass[64];
    float* msg = (float*)z;                      // [64][66] fp32, 16.9 KB

    int t = threadIdx.x;
    int l = t & 63;
    int w = t >> 6;
    int eb = blockIdx.x * 64;

    if (t < 64) {
        dsh[t] = dstS[eb + t];
        ssh[t] = srcS[eb + t];
        biasf[t] = bfv[t];
    } else if (t < 128) {
        biass[t - 64] = bsv[t - 64];
    }
    __syncthreads();

    // stage z rows: 192 (edge,section) pairs, each = 8 lanes x 16B
    {
        int sub = l >> 3, j = l & 7;
#pragma unroll
        for (int i = 0; i < 6; ++i) {
            int idx = i * 32 + w * 8 + sub;      // 0..191
            int e = idx & 63, sec = idx >> 6;
            const unsigned short* srcp =
                (sec == 0) ? hb + (size_t)dsh[e] * 64
              : (sec == 1) ? hb + (size_t)ssh[e] * 64
                           : eaSb + (size_t)(eb + e) * 64;
            *(uint4*)&z[e * ESTRIDE + sec * 64 + j * 8] =
                *(const uint4*)&srcp[j * 8];
        }
    }
    __syncthreads();

    // MFMA: C[64 e][32 cols] per wave = 4 row-tiles x 2 col-tiles x 6 K-steps
    int lm = l & 15, lg = l >> 4;
    f32x4 acc[4][2] = {};
#pragma unroll 1
    for (int ks = 0; ks < 6; ++ks) {
        int kofs = ks * 32 + lg * 8;
        bf16x8 a[4];
#pragma unroll
        for (int r = 0; r < 4; ++r)
            a[r] = *(const bf16x8*)&z[(16 * r + lm) * ESTRIDE + kofs];
#pragma unroll
        for (int c2 = 0; c2 < 2; ++c2) {
            int col = w * 32 + c2 * 16 + lm;
            bf16x8 b = *(const bf16x8*)&WbT[(size_t)col * KPAD + kofs];
#pragma unroll
            for (int r = 0; r < 4; ++r)
                acc[r][c2] = __builtin_amdgcn_mfma_f32_16x16x32_bf16(
                    a[r], b, acc[r][c2], 0, 0, 0);
        }
    }
    __syncthreads();   // z dead; msg region live

    // acc element (r,c2,j) -> edge e = 16r + 4*lg + j, col = w*32 + c2*16 + lm
    if (w >= 2) {      // s half: softplus, publish
#pragma unroll
        for (int c2 = 0; c2 < 2; ++c2) {
            int c = (w - 2) * 32 + c2 * 16 + lm;
            float bv = biass[c];
#pragma unroll
            for (int r = 0; r < 4; ++r)
#pragma unroll
                for (int j = 0; j < 4; ++j)
                    msg[(16 * r + 4 * lg + j) * 66 + c] =
                        softplusf_(acc[r][c2][j] + bv);
        }
    }
    __syncthreads();
    if (w < 2) {       // f half: sigmoid * softplus -> msg
#pragma unroll
        for (int c2 = 0; c2 < 2; ++c2) {
            int c = w * 32 + c2 * 16 + lm;
            float bv = biasf[c];
#pragma unroll
            for (int r = 0; r < 4; ++r)
#pragma unroll
                for (int j = 0; j < 4; ++j) {
                    int e = 16 * r + 4 * lg + j;
                    float m = sigmoidf_(acc[r][c2][j] + bv) * msg[e * 66 + c];
                    msg[e * 66 + c] = m;
                }
        }
    }
    __syncthreads();

    // aggregation: wave w -> edges [16w,16w+16), lane = column.
    // dst-sorted: run-accumulate, one contiguous 64-lane atomic per distinct dst
    {
        int e0 = w * 16;
        int cur = __builtin_amdgcn_readfirstlane(dsh[e0]);
        float a = 0.0f;
        for (int e = e0; e < e0 + 16; ++e) {
            a += msg[e * 66 + l];
            int nxt = (e + 1 < e0 + 16) ? __builtin_amdgcn_readfirstlane(dsh[e + 1]) : -1;
            if (nxt != cur) {
                atomicAdd(&agg[(size_t)cur * FEA + l], a);
                a = 0.0f;
                cur = nxt;
            }
        }
    }
}

// ---------------- BN stats / apply ----------------
__global__ __launch_bounds__(256) void k_bnstats(const float* __restrict__ agg,
                                                 float* __restrict__ stats) {
    int t = threadIdx.x, c = t & 63, w = t >> 6;
    float s = 0.0f, q = 0.0f;
    for (int r = blockIdx.x * 4 + w; r < N_NODES; r += gridDim.x * 4) {
        float v = agg[(size_t)r * FEA + c];
        s += v;
        q = fmaf(v, v, q);
    }
    __shared__ float red[2][256];
    red[0][t] = s;
    red[1][t] = q;
    __syncthreads();
    if (t < 64) {
        s = red[0][t] + red[0][t + 64] + red[0][t + 128] + red[0][t + 192];
        q = red[1][t] + red[1][t + 64] + red[1][t + 128] + red[1][t + 192];
        atomicAdd(&stats[t], s);
        atomicAdd(&stats[64 + t], q);
    }
}

__global__ __launch_bounds__(256) void k_bnapply(const float* __restrict__ agg,
                                                 const float* __restrict__ stats,
                                                 const float* __restrict__ gamma,
                                                 const float* __restrict__ beta,
                                                 float* __restrict__ h,
                                                 unsigned short* __restrict__ hb) {
    int idx = blockIdx.x * 256 + threadIdx.x;
    int c = idx & 63;
    float mu = stats[c] * (1.0f / N_NODES);
    float var = stats[64 + c] * (1.0f / N_NODES) - mu * mu;
    float rs = rsqrtf(var + 1e-5f);
    float v = agg[idx];
    float hn = h[idx] + (v - mu) * rs * gamma[c] + beta[c];
    h[idx] = hn;
    hb[idx] = f2bf(hn);
}

// ---------------- pool + head ----------------
__global__ __launch_bounds__(256) void k_pool(const float* __restrict__ h,
                                              const int* __restrict__ batch,
                                              float* __restrict__ psum,
                                              float* __restrict__ pcnt) {
    int g = blockIdx.x;
    int lo, hi;
    {
        int a = 0, b = N_NODES;
        while (a < b) { int m = (a + b) >> 1; if (batch[m] < g) a = m + 1; else b = m; }
        lo = a;
    }
    {
        int a = lo, b = N_NODES;
        while (a < b) { int m = (a + b) >> 1; if (batch[m] < g + 1) a = m + 1; else b = m; }
        hi = a;
    }
    int t = threadIdx.x, c = t & 63, w = t >> 6;
    float s = 0.0f;
    for (int r = lo + w; r < hi; r += 4) s += h[(size_t)r * FEA + c];
    __shared__ float red[256];
    red[t] = s;
    __syncthreads();
    if (t < 64) {
        psum[g * FEA + t] = red[t] + red[t + 64] + red[t + 128] + red[t + 192];
        if (t == 0) pcnt[g] = (float)(hi - lo);
    }
}

__global__ __launch_bounds__(256) void k_head(const float* __restrict__ psum,
                                              const float* __restrict__ pcnt,
                                              const float* __restrict__ W1, const float* __restrict__ b1,
                                              const float* __restrict__ W2, const float* __restrict__ b2,
                                              const float* __restrict__ W3, const float* __restrict__ b3,
                                              float* __restrict__ out) {
    int g = blockIdx.x, t = threadIdx.x;
    __shared__ float p[64], g1[256], g2[256];
    if (t < 64) p[t] = psum[g * FEA + t] / fmaxf(pcnt[g], 1.0f);
    __syncthreads();
    {
        float acc = b1[t];
#pragma unroll 8
        for (int k = 0; k < FEA; ++k) acc = fmaf(p[k], W1[k * HID + t], acc);
        g1[t] = softplusf_(acc);
    }
    __syncthreads();
    {
        float acc = b2[t];
#pragma unroll 8
        for (int k = 0; k < HID; ++k) acc = fmaf(g1[k], W2[k * HID + t], acc);
        g2[t] = softplusf_(acc);
    }
    __syncthreads();
    for (int c = t; c < OUT_PER_G; c += 256) {
        float acc = b3[c];
#pragma unroll 8
        for (int k = 0; k < HID; ++k) acc = fmaf(g2[k], W3[k * OUT_PER_G + c], acc);
        out[g * OUT_PER_G + c] = acc;
    }
}

extern "C" void kernel_launch(void* const* d_in, const int* in_sizes, int n_in,
                              void* d_out, int out_size, void* d_ws, size_t ws_size,
                              hipStream_t stream) {
    (void)in_sizes; (void)n_in; (void)out_size; (void)ws_size;
    const float* x    = (const float*)d_in[0];
    const int*   ei   = (const int*)d_in[1];
    const float* ea   = (const float*)d_in[2];
    const int*   batch= (const int*)d_in[3];
    const float* embW = (const float*)d_in[4];
    const float* embB = (const float*)d_in[5];
    const float* lfW  = (const float*)d_in[6];
    const float* lfB  = (const float*)d_in[7];
    const float* lsW  = (const float*)d_in[8];
    const float* lsB  = (const float*)d_in[9];
    const float* gam  = (const float*)d_in[10];
    const float* bet  = (const float*)d_in[11];
    const float* W1 = (const float*)d_in[12];
    const float* b1 = (const float*)d_in[13];
    const float* W2 = (const float*)d_in[14];
    const float* b2 = (const float*)d_in[15];
    const float* W3 = (const float*)d_in[16];
    const float* b3 = (const float*)d_in[17];

    const int* srcI = ei;             // edge_index[0] = source (x_j)
    const int* dstI = ei + N_EDGES;   // edge_index[1] = target (x_i)

    char* ws = (char*)d_ws;
    size_t off = 0;
    float* h      = (float*)(ws + off); off += HBYTES;                   // 25.6 MB
    float* agg    = (float*)(ws + off); off += HBYTES;                   // 25.6 MB
    float* stats  = (float*)(ws + off); off += 512;                      // joint memset w/ agg
    float* psum   = (float*)(ws + off); off += 32768;
    float* pcnt   = (float*)(ws + off); off += 512;
    unsigned short* hbuf = (unsigned short*)(ws + off); off += (size_t)N_NODES * 64 * 2;   // 12.8 MB
    unsigned short* eaSb = (unsigned short*)(ws + off); off += (size_t)N_EDGES * 64 * 2;   // 204.8 MB
    unsigned short* WbT  = (unsigned short*)(ws + off); off += (size_t)N_CONV * 128 * KPAD * 2;
    int*   cnt    = (int*)(ws + off);   off += (size_t)NPAD * 4;
    int*   bsum   = (int*)(ws + off);   off += 2048;
    int*   offs   = (int*)(ws + off);   off += (size_t)NPAD * 4;
    int*   cursor = (int*)(ws + off);   off += (size_t)NPAD * 4;
    int*   dstS   = (int*)(ws + off);   off += (size_t)N_EDGES * 4;
    int*   srcS   = (int*)(ws + off);   off += (size_t)N_EDGES * 4;
    int*   eidS   = (int*)(ws + off);   off += (size_t)N_EDGES * 4;

    // ---- one-time: sort edges by dst, pre-gather ea (sorted, bf16), pack W ----
    hipMemsetAsync(cnt, 0, (size_t)NPAD * 4, stream);
    hipMemsetAsync(cursor, 0, (size_t)NPAD * 4, stream);
    k_hist<<<(N_EDGES + 255) / 256, 256, 0, stream>>>(dstI, cnt);
    k_blocksum<<<NBLK, 256, 0, stream>>>(cnt, bsum);
    k_topscan<<<1, 512, 0, stream>>>(bsum);
    k_localscan<<<NBLK, 256, 0, stream>>>(cnt, bsum, offs);
    k_scatter<<<(N_EDGES + 255) / 256, 256, 0, stream>>>(dstI, srcI, offs, cursor,
                                                         dstS, srcS, eidS);
    k_eaprep<<<N_EDGES / 4, 256, 0, stream>>>(ea, eidS, eaSb);
    k_wprep<<<(N_CONV * 128 * KPAD + 255) / 256, 256, 0, stream>>>(lfW, lsW, WbT);

    k_embed<<<N_NODES * FEA / 256, 256, 0, stream>>>(x, embW, embB, h, hbuf);

    for (int L = 0; L < N_CONV; ++L) {
        hipMemsetAsync(agg, 0, HBYTES + 512, stream);  // agg + stats
        k_edge<<<N_EDGES / 64, 256, 0, stream>>>(hbuf, dstS, srcS, eaSb,
                                                 WbT + (size_t)L * 128 * KPAD,
                                                 lfB + L * FEA, lsB + L * FEA,
                                                 agg);
        k_bnstats<<<256, 256, 0, stream>>>(agg, stats);
        k_bnapply<<<N_NODES * FEA / 256, 256, 0, stream>>>(agg, stats,
                                                           gam + L * FEA, bet + L * FEA,
                                                           h, hbuf);
    }

    k_pool<<<NUM_GRAPHS, 256, 0, stream>>>(h, batch, psum, pcnt);
    k_head<<<NUM_GRAPHS, 256, 0, stream>>>(psum, pcnt, W1, b1, W2, b2, W3, b3,
                                           (float*)d_out);
}

// Round 4
// 1700.536 us; speedup vs baseline: 16.7079x; 1.2616x over previous
//
#include <hip/hip_runtime.h>
#include <math.h>

#define N_NODES 100000
#define N_EDGES 1600000
#define NUM_GRAPHS 128
#define ATOM_IN 92
#define FEA 64
#define EDGE_DIM 41
#define ZDIM 169
#define KPAD 192        // 64 h_dst + 64 h_src + 64 ea(padded)
#define N_CONV 5
#define HID 256
#define OUT_PER_G 384
#define NPAD 100096      // 391 * 256
#define NBLK 391
#define ESTRIDE 200      // bf16 elems per z row in LDS (192 + 8 pad: conflict-free)

#define HBYTES ((size_t)N_NODES * FEA * 4)   // 25,600,000

typedef __attribute__((ext_vector_type(8))) short bf16x8;
typedef __attribute__((ext_vector_type(4))) float f32x4;

__device__ __forceinline__ float sigmoidf_(float x) {
    return 1.0f / (1.0f + __expf(-x));
}
__device__ __forceinline__ float softplusf_(float x) {
    float a = fabsf(x);
    return fmaxf(x, 0.0f) + __logf(1.0f + __expf(-a));
}
__device__ __forceinline__ unsigned short f2bf(float f) {
    unsigned int u = __float_as_uint(f);
    u = (u + 0x7FFFu + ((u >> 16) & 1u)) >> 16;   // round-nearest-even
    return (unsigned short)u;
}

// ---------------- embed: h = x @ embW + embB (writes fp32 + bf16 copy) ------
__global__ __launch_bounds__(256) void k_embed(const float* __restrict__ x,
                                               const float* __restrict__ W,
                                               const float* __restrict__ b,
                                               float* __restrict__ h,
                                               unsigned short* __restrict__ hb) {
    int idx = blockIdx.x * 256 + threadIdx.x;
    int c = idx & 63;
    int n = __builtin_amdgcn_readfirstlane(idx >> 6);
    float acc = 0.0f;
#pragma unroll 4
    for (int k = 0; k < ATOM_IN; ++k)
        acc = fmaf(x[n * ATOM_IN + k], W[k * FEA + c], acc);
    acc += b[c];
    h[idx] = acc;
    hb[idx] = f2bf(acc);
}

// ---------------- counting sort of edges by dst ----------------
__global__ __launch_bounds__(256) void k_hist(const int* __restrict__ dst,
                                              int* __restrict__ cnt) {
    int e = blockIdx.x * 256 + threadIdx.x;
    if (e < N_EDGES) atomicAdd(&cnt[dst[e]], 1);
}

__global__ __launch_bounds__(256) void k_blocksum(const int* __restrict__ cnt,
                                                  int* __restrict__ bsum) {
    __shared__ int s[256];
    int t = threadIdx.x;
    s[t] = cnt[blockIdx.x * 256 + t];
    __syncthreads();
    for (int o = 128; o > 0; o >>= 1) {
        if (t < o) s[t] += s[t + o];
        __syncthreads();
    }
    if (t == 0) bsum[blockIdx.x] = s[0];
}

__global__ __launch_bounds__(512) void k_topscan(int* __restrict__ bsum) {
    __shared__ int s[512];
    int t = threadIdx.x;
    int v = (t < NBLK) ? bsum[t] : 0;
    s[t] = v;
    __syncthreads();
    for (int o = 1; o < 512; o <<= 1) {
        int x = (t >= o) ? s[t - o] : 0;
        __syncthreads();
        s[t] += x;
        __syncthreads();
    }
    if (t < NBLK) bsum[t] = s[t] - v;  // exclusive
}

__global__ __launch_bounds__(256) void k_localscan(const int* __restrict__ cnt,
                                                   const int* __restrict__ bsum,
                                                   int* __restrict__ offs) {
    __shared__ int s[256];
    int t = threadIdx.x;
    int i = blockIdx.x * 256 + t;
    int v = cnt[i];
    s[t] = v;
    __syncthreads();
    for (int o = 1; o < 256; o <<= 1) {
        int x = (t >= o) ? s[t - o] : 0;
        __syncthreads();
        s[t] += x;
        __syncthreads();
    }
    offs[i] = bsum[blockIdx.x] + s[t] - v;  // exclusive prefix
}

// scatter edges to dst-sorted order AND copy ea rows (fp32->bf16, zero-pad to
// 64) directly to the sorted slot. ea read is sequential (original order);
// eaSb write is a wave-cooperative 128B-burst scatter (8 lanes x 16B).
__global__ __launch_bounds__(256) void k_scatter_ea(const int* __restrict__ dst,
                                                    const int* __restrict__ src,
                                                    const float* __restrict__ ea,
                                                    const int* __restrict__ offs,
                                                    int* __restrict__ cursor,
                                                    int* __restrict__ dstS,
                                                    int* __restrict__ srcS,
                                                    unsigned short* __restrict__ eaSb) {
    __shared__ int p_sh[256];
    int t = threadIdx.x;
    int e = blockIdx.x * 256 + t;          // N_EDGES % 256 == 0
    int d = dst[e];
    int p = offs[d] + atomicAdd(&cursor[d], 1);
    dstS[p] = d;
    srcS[p] = src[e];
    p_sh[t] = p;
    __syncthreads();

    int row = t >> 3, j = t & 7;           // 8 lanes per row
#pragma unroll
    for (int i = 0; i < 8; ++i, row += 32) {
        int ge = blockIdx.x * 256 + row;
        int pp = p_sh[row];
        const float* srcp = ea + (size_t)ge * EDGE_DIM;
        unsigned short outv[8];
#pragma unroll
        for (int q = 0; q < 8; ++q) {
            int col = j * 8 + q;
            float v = (col < EDGE_DIM) ? srcp[col] : 0.0f;
            outv[q] = f2bf(v);
        }
        *(uint4*)&eaSb[(size_t)pp * 64 + j * 8] = *(uint4*)outv;
    }
}

// ---------------- weight pack: WbT[L][c][k] = bf16(W[k][c]), k>=169 -> 0 ----
// c in [0,64) -> Wf col c ; c in [64,128) -> Ws col c-64.
__global__ __launch_bounds__(256) void k_wprep(const float* __restrict__ lfW,
                                               const float* __restrict__ lsW,
                                               unsigned short* __restrict__ WbT) {
    int idx = blockIdx.x * 256 + threadIdx.x;
    if (idx >= N_CONV * 128 * KPAD) return;
    int k = idx % KPAD;
    int c = (idx / KPAD) % 128;
    int L = idx / (KPAD * 128);
    float v = 0.0f;
    if (k < ZDIM) {
        const float* W = ((c < 64) ? lfW : lsW) + (size_t)L * ZDIM * FEA;
        v = W[k * FEA + (c & 63)];
    }
    WbT[idx] = f2bf(v);
}

// ---------------- edge kernel: MFMA over z=[h_d|h_s|ea] (bf16) --------------
// block = 64 dst-sorted edges, 4 waves. Wave w owns output cols [16w,16w+16)
// for BOTH f and s -> msg formed fully in-register (no cross-wave exchange).
__global__ __launch_bounds__(256) void k_edge(const unsigned short* __restrict__ hb,
                                              const int* __restrict__ dstS,
                                              const int* __restrict__ srcS,
                                              const unsigned short* __restrict__ eaSb,
                                              const unsigned short* __restrict__ WbT,
                                              const float* __restrict__ bfv,
                                              const float* __restrict__ bsv,
                                              float* __restrict__ agg) {
    __shared__ unsigned short z[64 * ESTRIDE];   // 25.6 KB; reused as msg after MFMA
    __shared__ int dsh[64], ssh[64];
    __shared__ float biasf[64], biass[64];
    float* msg = (float*)z;                      // [64][66] fp32, 16.9 KB

    int t = threadIdx.x;
    int l = t & 63;
    int w = t >> 6;
    int eb = blockIdx.x * 64;

    if (t < 64) {
        dsh[t] = dstS[eb + t];
        ssh[t] = srcS[eb + t];
        biasf[t] = bfv[t];
    } else if (t < 128) {
        biass[t - 64] = bsv[t - 64];
    }
    __syncthreads();

    // stage z rows: 192 (edge,section) pairs, each = 8 lanes x 16B
    {
        int sub = l >> 3, j = l & 7;
#pragma unroll
        for (int i = 0; i < 6; ++i) {
            int idx = i * 32 + w * 8 + sub;      // 0..191
            int e = idx & 63, sec = idx >> 6;
            const unsigned short* srcp =
                (sec == 0) ? hb + (size_t)dsh[e] * 64
              : (sec == 1) ? hb + (size_t)ssh[e] * 64
                           : eaSb + (size_t)(eb + e) * 64;
            *(uint4*)&z[e * ESTRIDE + sec * 64 + j * 8] =
                *(const uint4*)&srcp[j * 8];
        }
    }
    __syncthreads();

    // MFMA: per wave, C[64 e][16 cols] for f AND s. 4 row-tiles x 6 K-steps.
    int lm = l & 15, lg = l >> 4;
    int col = w * 16 + lm;
    f32x4 accF[4] = {};
    f32x4 accS[4] = {};
#pragma unroll 1
    for (int ks = 0; ks < 6; ++ks) {
        int kofs = ks * 32 + lg * 8;
        bf16x8 a[4];
#pragma unroll
        for (int r = 0; r < 4; ++r)
            a[r] = *(const bf16x8*)&z[(16 * r + lm) * ESTRIDE + kofs];
        bf16x8 bF = *(const bf16x8*)&WbT[(size_t)col * KPAD + kofs];
        bf16x8 bS = *(const bf16x8*)&WbT[(size_t)(64 + col) * KPAD + kofs];
#pragma unroll
        for (int r = 0; r < 4; ++r) {
            accF[r] = __builtin_amdgcn_mfma_f32_16x16x32_bf16(a[r], bF, accF[r], 0, 0, 0);
            accS[r] = __builtin_amdgcn_mfma_f32_16x16x32_bf16(a[r], bS, accS[r], 0, 0, 0);
        }
    }
    __syncthreads();   // all waves done reading z; msg region live

    // epilogue fully in-register: msg = sigmoid(f+bf) * softplus(s+bs)
    // acc element (r,j) -> edge e = 16r + 4*lg + j, this thread's col.
    {
        float bfc = biasf[col], bsc = biass[col];
#pragma unroll
        for (int r = 0; r < 4; ++r)
#pragma unroll
            for (int j = 0; j < 4; ++j) {
                int e = 16 * r + 4 * lg + j;
                msg[e * 66 + col] =
                    sigmoidf_(accF[r][j] + bfc) * softplusf_(accS[r][j] + bsc);
            }
    }
    __syncthreads();

    // aggregation: wave w -> edges [16w,16w+16), lane = column.
    // dst-sorted: run-accumulate, one contiguous 64-lane atomic per distinct dst
    {
        int e0 = w * 16;
        int cur = __builtin_amdgcn_readfirstlane(dsh[e0]);
        float a = 0.0f;
        for (int e = e0; e < e0 + 16; ++e) {
            a += msg[e * 66 + l];
            int nxt = (e + 1 < e0 + 16) ? __builtin_amdgcn_readfirstlane(dsh[e + 1]) : -1;
            if (nxt != cur) {
                atomicAdd(&agg[(size_t)cur * FEA + l], a);
                a = 0.0f;
                cur = nxt;
            }
        }
    }
}

// ---------------- BN stats / apply ----------------
__global__ __launch_bounds__(256) void k_bnstats(const float* __restrict__ agg,
                                                 float* __restrict__ stats) {
    int t = threadIdx.x, c = t & 63, w = t >> 6;
    float s = 0.0f, q = 0.0f;
    for (int r = blockIdx.x * 4 + w; r < N_NODES; r += gridDim.x * 4) {
        float v = agg[(size_t)r * FEA + c];
        s += v;
        q = fmaf(v, v, q);
    }
    __shared__ float red[2][256];
    red[0][t] = s;
    red[1][t] = q;
    __syncthreads();
    if (t < 64) {
        s = red[0][t] + red[0][t + 64] + red[0][t + 128] + red[0][t + 192];
        q = red[1][t] + red[1][t + 64] + red[1][t + 128] + red[1][t + 192];
        atomicAdd(&stats[t], s);
        atomicAdd(&stats[64 + t], q);
    }
}

__global__ __launch_bounds__(256) void k_bnapply(const float* __restrict__ agg,
                                                 const float* __restrict__ stats,
                                                 const float* __restrict__ gamma,
                                                 const float* __restrict__ beta,
                                                 float* __restrict__ h,
                                                 unsigned short* __restrict__ hb) {
    int idx = blockIdx.x * 256 + threadIdx.x;
    int c = idx & 63;
    float mu = stats[c] * (1.0f / N_NODES);
    float var = stats[64 + c] * (1.0f / N_NODES) - mu * mu;
    float rs = rsqrtf(var + 1e-5f);
    float v = agg[idx];
    float hn = h[idx] + (v - mu) * rs * gamma[c] + beta[c];
    h[idx] = hn;
    hb[idx] = f2bf(hn);
}

// ---------------- pool + head ----------------
__global__ __launch_bounds__(256) void k_pool(const float* __restrict__ h,
                                              const int* __restrict__ batch,
                                              float* __restrict__ psum,
                                              float* __restrict__ pcnt) {
    int g = blockIdx.x;
    int lo, hi;
    {
        int a = 0, b = N_NODES;
        while (a < b) { int m = (a + b) >> 1; if (batch[m] < g) a = m + 1; else b = m; }
        lo = a;
    }
    {
        int a = lo, b = N_NODES;
        while (a < b) { int m = (a + b) >> 1; if (batch[m] < g + 1) a = m + 1; else b = m; }
        hi = a;
    }
    int t = threadIdx.x, c = t & 63, w = t >> 6;
    float s = 0.0f;
    for (int r = lo + w; r < hi; r += 4) s += h[(size_t)r * FEA + c];
    __shared__ float red[256];
    red[t] = s;
    __syncthreads();
    if (t < 64) {
        psum[g * FEA + t] = red[t] + red[t + 64] + red[t + 128] + red[t + 192];
        if (t == 0) pcnt[g] = (float)(hi - lo);
    }
}

__global__ __launch_bounds__(256) void k_head(const float* __restrict__ psum,
                                              const float* __restrict__ pcnt,
                                              const float* __restrict__ W1, const float* __restrict__ b1,
                                              const float* __restrict__ W2, const float* __restrict__ b2,
                                              const float* __restrict__ W3, const float* __restrict__ b3,
                                              float* __restrict__ out) {
    int g = blockIdx.x, t = threadIdx.x;
    __shared__ float p[64], g1[256], g2[256];
    if (t < 64) p[t] = psum[g * FEA + t] / fmaxf(pcnt[g], 1.0f);
    __syncthreads();
    {
        float acc = b1[t];
#pragma unroll 8
        for (int k = 0; k < FEA; ++k) acc = fmaf(p[k], W1[k * HID + t], acc);
        g1[t] = softplusf_(acc);
    }
    __syncthreads();
    {
        float acc = b2[t];
#pragma unroll 8
        for (int k = 0; k < HID; ++k) acc = fmaf(g1[k], W2[k * HID + t], acc);
        g2[t] = softplusf_(acc);
    }
    __syncthreads();
    for (int c = t; c < OUT_PER_G; c += 256) {
        float acc = b3[c];
#pragma unroll 8
        for (int k = 0; k < HID; ++k) acc = fmaf(g2[k], W3[k * OUT_PER_G + c], acc);
        out[g * OUT_PER_G + c] = acc;
    }
}

extern "C" void kernel_launch(void* const* d_in, const int* in_sizes, int n_in,
                              void* d_out, int out_size, void* d_ws, size_t ws_size,
                              hipStream_t stream) {
    (void)in_sizes; (void)n_in; (void)out_size; (void)ws_size;
    const float* x    = (const float*)d_in[0];
    const int*   ei   = (const int*)d_in[1];
    const float* ea   = (const float*)d_in[2];
    const int*   batch= (const int*)d_in[3];
    const float* embW = (const float*)d_in[4];
    const float* embB = (const float*)d_in[5];
    const float* lfW  = (const float*)d_in[6];
    const float* lfB  = (const float*)d_in[7];
    const float* lsW  = (const float*)d_in[8];
    const float* lsB  = (const float*)d_in[9];
    const float* gam  = (const float*)d_in[10];
    const float* bet  = (const float*)d_in[11];
    const float* W1 = (const float*)d_in[12];
    const float* b1 = (const float*)d_in[13];
    const float* W2 = (const float*)d_in[14];
    const float* b2 = (const float*)d_in[15];
    const float* W3 = (const float*)d_in[16];
    const float* b3 = (const float*)d_in[17];

    const int* srcI = ei;             // edge_index[0] = source (x_j)
    const int* dstI = ei + N_EDGES;   // edge_index[1] = target (x_i)

    char* ws = (char*)d_ws;
    size_t off = 0;
    float* h      = (float*)(ws + off); off += HBYTES;                   // 25.6 MB
    float* agg    = (float*)(ws + off); off += HBYTES;                   // 25.6 MB
    float* stats  = (float*)(ws + off); off += 512;                      // joint memset w/ agg
    float* psum   = (float*)(ws + off); off += 32768;
    float* pcnt   = (float*)(ws + off); off += 512;
    unsigned short* hbuf = (unsigned short*)(ws + off); off += (size_t)N_NODES * 64 * 2;   // 12.8 MB
    unsigned short* eaSb = (unsigned short*)(ws + off); off += (size_t)N_EDGES * 64 * 2;   // 204.8 MB
    unsigned short* WbT  = (unsigned short*)(ws + off); off += (size_t)N_CONV * 128 * KPAD * 2;
    int*   cnt    = (int*)(ws + off);   off += (size_t)NPAD * 4;
    int*   bsum   = (int*)(ws + off);   off += 2048;
    int*   offs   = (int*)(ws + off);   off += (size_t)NPAD * 4;
    int*   cursor = (int*)(ws + off);   off += (size_t)NPAD * 4;
    int*   dstS   = (int*)(ws + off);   off += (size_t)N_EDGES * 4;
    int*   srcS   = (int*)(ws + off);   off += (size_t)N_EDGES * 4;

    // ---- one-time per launch: sort edges by dst (fused ea gather), pack W ----
    hipMemsetAsync(cnt, 0, (size_t)NPAD * 4, stream);
    hipMemsetAsync(cursor, 0, (size_t)NPAD * 4, stream);
    k_hist<<<(N_EDGES + 255) / 256, 256, 0, stream>>>(dstI, cnt);
    k_blocksum<<<NBLK, 256, 0, stream>>>(cnt, bsum);
    k_topscan<<<1, 512, 0, stream>>>(bsum);
    k_localscan<<<NBLK, 256, 0, stream>>>(cnt, bsum, offs);
    k_scatter_ea<<<N_EDGES / 256, 256, 0, stream>>>(dstI, srcI, ea, offs, cursor,
                                                    dstS, srcS, eaSb);
    k_wprep<<<(N_CONV * 128 * KPAD + 255) / 256, 256, 0, stream>>>(lfW, lsW, WbT);

    k_embed<<<N_NODES * FEA / 256, 256, 0, stream>>>(x, embW, embB, h, hbuf);

    for (int L = 0; L < N_CONV; ++L) {
        hipMemsetAsync(agg, 0, HBYTES + 512, stream);  // agg + stats
        k_edge<<<N_EDGES / 64, 256, 0, stream>>>(hbuf, dstS, srcS, eaSb,
                                                 WbT + (size_t)L * 128 * KPAD,
                                                 lfB + L * FEA, lsB + L * FEA,
                                                 agg);
        k_bnstats<<<256, 256, 0, stream>>>(agg, stats);
        k_bnapply<<<N_NODES * FEA / 256, 256, 0, stream>>>(agg, stats,
                                                           gam + L * FEA, bet + L * FEA,
                                                           h, hbuf);
    }

    k_pool<<<NUM_GRAPHS, 256, 0, stream>>>(h, batch, psum, pcnt);
    k_head<<<NUM_GRAPHS, 256, 0, stream>>>(psum, pcnt, W1, b1, W2, b2, W3, b3,
                                           (float*)d_out);
}